// Round 10
// baseline (222.633 us; speedup 1.0000x reference)
//
#include <hip/hip_runtime.h>
#include <hip/hip_bf16.h>
#include <math.h>

typedef __attribute__((ext_vector_type(8))) __bf16 bf16x8;
typedef __attribute__((ext_vector_type(4))) float f32x4;

#define IN_DIM 2048
#define NH1 128
#define NH2 64
#define KDIM 1024

__device__ inline f32x4 mfma16(bf16x8 a, bf16x8 b, f32x4 c) {
    return __builtin_amdgcn_mfma_f32_16x16x32_bf16(a, b, c, 0, 0, 0);
}

__device__ inline void gld16(const void* g, void* l) {
    __builtin_amdgcn_global_load_lds(
        (const __attribute__((address_space(1))) void*)g,
        (__attribute__((address_space(3))) void*)l, 16, 0, 0);
}

// ---------------------------------------------------------------------------
// prep: permute W1/W2 into MFMA-fragment order (bf16), pack basis rows with
// c_j = head_w[j] * exp(-||b_j||^2).
// Fragment convention (A and B identical): within a 32-k x 16-col tile,
// lane l, elem e  ->  k = (l>>4)*8 + e , col/row = l&15.
// ---------------------------------------------------------------------------
__global__ void prep_kernel(const float* __restrict__ W1,
                            const float* __restrict__ W2,
                            const float* __restrict__ basis,
                            const float* __restrict__ head_w,
                            __bf16* __restrict__ w1f,
                            __bf16* __restrict__ w2f,
                            float* __restrict__ bp) {
    int idx = blockIdx.x * 256 + threadIdx.x;   // 0 .. 262143
    if (idx < IN_DIM * NH1) {
        int ks = idx >> 12;
        int rem = idx & 4095;
        int c = rem >> 9;
        int q = rem & 511;
        int l = q >> 3, e = q & 7;
        int k = ks * 32 + ((l >> 4) << 3) + e;
        int col = (c << 4) + (l & 15);
        w1f[idx] = (__bf16)W1[k * NH1 + col];
    }
    if (idx < NH1 * NH2) {
        int cb = idx >> 9;
        int c2 = cb >> 2, kb = cb & 3;
        int q = idx & 511;
        int l = q >> 3, e = q & 7;
        int k = kb * 32 + ((l >> 4) << 3) + e;
        int col = (c2 << 4) + (l & 15);
        w2f[idx] = (__bf16)W2[k * NH2 + col];
    }
    if (idx < KDIM) {
        const float* b = basis + idx * 5;
        float n2 = b[0]*b[0] + b[1]*b[1] + b[2]*b[2] + b[3]*b[3] + b[4]*b[4];
        float* o = bp + idx * 8;
        o[0] = b[0]; o[1] = b[1]; o[2] = b[2]; o[3] = b[3]; o[4] = b[4];
        o[5] = 1.0f;
        o[6] = head_w[idx] * expf(-n2);   // gamma = 1
        o[7] = 0.0f;
    }
}

// ---------------------------------------------------------------------------
// fused main — free-running wave-autonomous structure, ZERO barriers.
//   1 wave / block, 16 rows. A: 2-slot wave-private LDS ring (2x2KB), staged
//   by 2 gld16/iter with XOR-pre-swizzled source. B (w1f, L2): double-
//   buffered in registers, 8 dwordx4/iter. Exact counted vmcnt:
//   steady wait = vmcnt(10) (keeps B(t+1)[8] + A(t+1)[2], drains A(t)/B(t)).
//   A(t+2) is issued only after lgkmcnt(0) (slot t fragments in VGPRs).
//   Epilogue wave-private: h1 in LDS @0 (4KB, XOR-swz), z5 @4096 (512B),
//   shuffle reductions, lanes 0-15 store out.
// ---------------------------------------------------------------------------
__launch_bounds__(64, 3)
__global__ void fused_main(const float* __restrict__ x,
                           const __bf16* __restrict__ w1f,
                           const float* __restrict__ b1,
                           const __bf16* __restrict__ w2f,
                           const float* __restrict__ b2,
                           const float* __restrict__ W3,
                           const float* __restrict__ b3,
                           const float* __restrict__ conv_k,
                           const float* __restrict__ conv_b,
                           const float* __restrict__ bp,
                           const float* __restrict__ head_b,
                           float* __restrict__ out) {
    __shared__ __align__(16) char smem[4608];

    const int l = threadIdx.x;   // 0..63, one wave
    const int r = l & 15;        // fragment col/row index
    const int j = l >> 4;        // fragment k-group
    const int row0 = blockIdx.x * 16;

    // ---- A staging sources: instr q covers rows 8q..8q+7 ------------------
    // lane l -> LDS slot chunk l&7 of row l>>3; source chunk (l&7)^((l>>3)&7)
    const char* xb = (const char*)x;
    unsigned aByte[2];
#pragma unroll
    for (int q = 0; q < 2; ++q) {
        int rw = q * 8 + (l >> 3);
        aByte[q] = (unsigned)(row0 + rw) * (IN_DIM * 4)
                 + ((unsigned)((l & 7) ^ ((l >> 3) & 7)) << 4);
    }
    const char* wBb = (const char*)w1f + l * 16;

#define STAGE_A(T)                                                            \
    {                                                                         \
        gld16(xb + aByte[0] + (unsigned)(T) * 128u,                           \
              smem + (((T) & 1) << 11));                                      \
        gld16(xb + aByte[1] + (unsigned)(T) * 128u,                           \
              smem + (((T) & 1) << 11) + 1024);                               \
        __builtin_amdgcn_sched_barrier(0);                                    \
    }
#define LOADB(BANK, T)                                                        \
    {                                                                         \
        _Pragma("unroll")                                                     \
        for (int c = 0; c < 8; ++c)                                           \
            BANK[c] = *(const bf16x8*)(wBb + (size_t)(T) * 8192 + c * 1024);  \
        __builtin_amdgcn_sched_barrier(0);                                    \
    }

    f32x4 acc[8];
#pragma unroll
    for (int c = 0; c < 8; ++c) acc[c] = (f32x4){0.f, 0.f, 0.f, 0.f};

    bf16x8 Bc[8], Bn[8];

    // body: [LOADB next] [vmcnt(10)] [ds_read slot(t) + cvt] [lgkmcnt(0)]
    //        [STAGE A(t+2)] [8 MFMA with current bank]
#define BODY(T, CUR, NXT, DO_B, DO_A)                                         \
    {                                                                         \
        if (DO_B) { LOADB(NXT, (T) + 1) }                                     \
        if (DO_B) { asm volatile("s_waitcnt vmcnt(10)" ::: "memory"); }       \
        else      { asm volatile("s_waitcnt vmcnt(0)"  ::: "memory"); }       \
        __builtin_amdgcn_sched_barrier(0);                                    \
        const char* ar = smem + (((T) & 1) << 11) + r * 128;                  \
        f32x4 f0 = *(const f32x4*)(ar + (((2 * j)     ^ (r & 7)) << 4));      \
        f32x4 f1 = *(const f32x4*)(ar + (((2 * j + 1) ^ (r & 7)) << 4));      \
        asm volatile("s_waitcnt lgkmcnt(0)" ::: "memory");                    \
        __builtin_amdgcn_sched_barrier(0);                                    \
        if (DO_A) { STAGE_A((T) + 2) }                                        \
        bf16x8 Af;                                                            \
        Af[0] = (__bf16)f0.x; Af[1] = (__bf16)f0.y;                           \
        Af[2] = (__bf16)f0.z; Af[3] = (__bf16)f0.w;                           \
        Af[4] = (__bf16)f1.x; Af[5] = (__bf16)f1.y;                           \
        Af[6] = (__bf16)f1.z; Af[7] = (__bf16)f1.w;                           \
        _Pragma("unroll")                                                     \
        for (int c = 0; c < 8; ++c) acc[c] = mfma16(Af, CUR[c], acc[c]);      \
    }

    // ---- prologue: A(0), B(0), A(1) = 12 outstanding ----------------------
    STAGE_A(0)
    LOADB(Bc, 0)
    STAGE_A(1)

    // ---- main loop: t = 0..61 (unroll-2 for static B bank swap) ----------
#pragma unroll 1
    for (int t = 0; t < 62; t += 2) {
        BODY(t,     Bc, Bn, 1, 1)       // even: cur=Bc, load Bn
        BODY(t + 1, Bn, Bc, 1, 1)       // odd:  cur=Bn, load Bc
    }
    BODY(62, Bc, Bn, 1, 0)              // loads B(63), no A-stage
    BODY(63, Bn, Bc, 0, 0)              // drains everything (vmcnt 0)

    // ---- epilogue: h1 = relu(acc + b1) -> wave-private LDS [16][128] ------
    // byte = row*256 + ((chunk ^ (row&7))<<4) + (r&7)*2, chunk = col>>3
    {
#pragma unroll
        for (int c = 0; c < 8; ++c) {
            float bv = b1[c * 16 + r];
#pragma unroll
            for (int rr = 0; rr < 4; ++rr) {
                int row = j * 4 + rr;
                int col = c * 16 + r;
                int chunk = col >> 3;
                unsigned byte = row * 256 + (((chunk) ^ (row & 7)) << 4)
                              + (r & 7) * 2;
                float v = fmaxf(acc[c][rr] + bv, 0.f);
                *(__bf16*)(smem + byte) = (__bf16)v;
            }
        }
    }
    asm volatile("s_waitcnt lgkmcnt(0)" ::: "memory");
    __builtin_amdgcn_sched_barrier(0);

    // ---- GEMM2: h2 = relu(h1 @ W2 + b2) ----------------------------------
    f32x4 acc2[4];
#pragma unroll
    for (int c2 = 0; c2 < 4; ++c2) acc2[c2] = (f32x4){0.f, 0.f, 0.f, 0.f};
#pragma unroll
    for (int kb = 0; kb < 4; ++kb) {
        const char* ap = smem + r * 256 + (((kb * 4 + j) ^ (r & 7)) << 4);
        bf16x8 A2 = *(const bf16x8*)ap;
#pragma unroll
        for (int c2 = 0; c2 < 4; ++c2) {
            bf16x8 B2 = *(const bf16x8*)(w2f + (((c2 << 2) + kb) << 9) + l * 8);
            acc2[c2] = mfma16(A2, B2, acc2[c2]);
        }
    }

    // ---- GEMM3 + conv/sigmoid -> z5 --------------------------------------
    float b2v[4];
#pragma unroll
    for (int c2 = 0; c2 < 4; ++c2) b2v[c2] = b2[c2 * 16 + r];
    float w3l[4][4];
#pragma unroll
    for (int c2 = 0; c2 < 4; ++c2) {
        f32x4 t4 = *(const f32x4*)&W3[(c2 * 16 + r) * 4];
        w3l[c2][0] = t4.x; w3l[c2][1] = t4.y;
        w3l[c2][2] = t4.z; w3l[c2][3] = t4.w;
    }
    float h2v[4][4];
#pragma unroll
    for (int c2 = 0; c2 < 4; ++c2)
#pragma unroll
        for (int rr = 0; rr < 4; ++rr)
            h2v[c2][rr] = fmaxf(acc2[c2][rr] + b2v[c2], 0.f);

    float pz[4][4];
#pragma unroll
    for (int rr = 0; rr < 4; ++rr)
#pragma unroll
        for (int jj = 0; jj < 4; ++jj) {
            float s = 0.f;
#pragma unroll
            for (int c2 = 0; c2 < 4; ++c2) s = fmaf(h2v[c2][rr], w3l[c2][jj], s);
            pz[rr][jj] = s;
        }
#pragma unroll
    for (int off = 1; off < 16; off <<= 1)
#pragma unroll
        for (int rr = 0; rr < 4; ++rr)
#pragma unroll
            for (int jj = 0; jj < 4; ++jj)
                pz[rr][jj] += __shfl_xor(pz[rr][jj], off, 64);

    const float ck0 = conv_k[0], ck1 = conv_k[1], ck2 = conv_k[2], ck3 = conv_k[3];
    const float cbv = conv_b[0];
    const float b30 = b3[0], b31 = b3[1], b32 = b3[2], b33 = b3[3];
    const float L2E = 1.44269504088896340736f;

    float (*z5s)[8] = (float(*)[8])(smem + 4096);
    if (r == 0) {
#pragma unroll
        for (int rr = 0; rr < 4; ++rr) {
            int rl = (j << 2) + rr;
            float z0 = pz[rr][0] + b30;
            float z1 = pz[rr][1] + b31;
            float z2 = pz[rr][2] + b32;
            float z3 = pz[rr][3] + b33;
            float s = fmaf(z0, ck0, fmaf(z1, ck1, fmaf(z2, ck2, fmaf(z3, ck3, cbv))));
            float sg = 1.f / (1.f + expf(-s));
            float n2 = z0*z0 + z1*z1 + z2*z2 + z3*z3 + sg*sg;
            z5s[rl][0] = 2.f * L2E * z0;
            z5s[rl][1] = 2.f * L2E * z1;
            z5s[rl][2] = 2.f * L2E * z2;
            z5s[rl][3] = 2.f * L2E * z3;
            z5s[rl][4] = 2.f * L2E * sg;
            z5s[rl][5] = -L2E * n2;
        }
    }
    asm volatile("s_waitcnt lgkmcnt(0)" ::: "memory");
    __builtin_amdgcn_sched_barrier(0);

    // ---- RBF + head: lane -> (row=r, basis chunk j*256) ------------------
    f32x4 za = *(const f32x4*)&z5s[r][0];
    float z4s = z5s[r][4];
    float z5c = z5s[r][5];
    const float* bpp = bp + (size_t)j * 256 * 8;
    float accum = 0.f;
#pragma unroll 4
    for (int jb = 0; jb < 256; ++jb) {
        f32x4 q0 = *(const f32x4*)&bpp[jb * 8];
        f32x4 q1 = *(const f32x4*)&bpp[jb * 8 + 4];
        float arg = fmaf(za.x, q0.x,
                    fmaf(za.y, q0.y,
                    fmaf(za.z, q0.z,
                    fmaf(za.w, q0.w,
                    fmaf(z4s, q1.x, z5c)))));
        accum = fmaf(q1.z, exp2f(arg), accum);
    }
    accum += __shfl_xor(accum, 16, 64);
    accum += __shfl_xor(accum, 32, 64);
    if (l < 16) out[row0 + l] = accum + head_b[0];
}

// ---------------------------------------------------------------------------
extern "C" void kernel_launch(void* const* d_in, const int* in_sizes, int n_in,
                              void* d_out, int out_size, void* d_ws, size_t ws_size,
                              hipStream_t stream) {
    const float* x     = (const float*)d_in[0];
    const float* W1    = (const float*)d_in[1];
    const float* b1    = (const float*)d_in[2];
    const float* W2    = (const float*)d_in[3];
    const float* b2    = (const float*)d_in[4];
    const float* W3    = (const float*)d_in[5];
    const float* b3    = (const float*)d_in[6];
    const float* ck    = (const float*)d_in[7];
    const float* cb    = (const float*)d_in[8];
    const float* basis = (const float*)d_in[9];
    const float* hwv   = (const float*)d_in[10];
    const float* hb    = (const float*)d_in[11];

    __bf16* w1f = (__bf16*)d_ws;                                 // 524288 B
    __bf16* w2f = (__bf16*)((char*)d_ws + 524288);               // 16384 B
    float*  bpp = (float*)((char*)d_ws + 524288 + 16384);        // 32768 B

    prep_kernel<<<1024, 256, 0, stream>>>(W1, W2, basis, hwv, w1f, w2f, bpp);
    fused_main<<<4096, 64, 0, stream>>>(x, w1f, b1, w2f, b2, W3, b3, ck, cb,
                                        bpp, hb, (float*)d_out);
}

// Round 11
// 163.444 us; speedup vs baseline: 1.3621x; 1.3621x over previous
//
#include <hip/hip_runtime.h>
#include <hip/hip_bf16.h>
#include <math.h>

typedef __attribute__((ext_vector_type(8))) __bf16 bf16x8;
typedef __attribute__((ext_vector_type(4))) float f32x4;

#define IN_DIM 2048
#define NH1 128
#define NH2 64
#define KDIM 1024

__device__ inline f32x4 mfma16(bf16x8 a, bf16x8 b, f32x4 c) {
    return __builtin_amdgcn_mfma_f32_16x16x32_bf16(a, b, c, 0, 0, 0);
}

__device__ inline void gld16(const void* g, void* l) {
    __builtin_amdgcn_global_load_lds(
        (const __attribute__((address_space(1))) void*)g,
        (__attribute__((address_space(3))) void*)l, 16, 0, 0);
}
// NT (CPol bit1) — stream policy for the read-once x stream: no L2/L3 alloc.
__device__ inline void gld16nt(const void* g, void* l) {
    __builtin_amdgcn_global_load_lds(
        (const __attribute__((address_space(1))) void*)g,
        (__attribute__((address_space(3))) void*)l, 16, 0, 2);
}

// ---------------------------------------------------------------------------
// prep: permute W1/W2 into MFMA-fragment order (bf16), pack basis rows with
// c_j = head_w[j] * exp(-||b_j||^2).
// Fragment convention (A and B identical): within a 32-k x 16-col tile,
// lane l, elem e  ->  k = (l>>4)*8 + e , col/row = l&15.
// ---------------------------------------------------------------------------
__global__ void prep_kernel(const float* __restrict__ W1,
                            const float* __restrict__ W2,
                            const float* __restrict__ basis,
                            const float* __restrict__ head_w,
                            __bf16* __restrict__ w1f,
                            __bf16* __restrict__ w2f,
                            float* __restrict__ bp) {
    int idx = blockIdx.x * 256 + threadIdx.x;   // 0 .. 262143
    if (idx < IN_DIM * NH1) {
        int ks = idx >> 12;
        int rem = idx & 4095;
        int c = rem >> 9;
        int q = rem & 511;
        int l = q >> 3, e = q & 7;
        int k = ks * 32 + ((l >> 4) << 3) + e;
        int col = (c << 4) + (l & 15);
        w1f[idx] = (__bf16)W1[k * NH1 + col];
    }
    if (idx < NH1 * NH2) {
        int cb = idx >> 9;
        int c2 = cb >> 2, kb = cb & 3;
        int q = idx & 511;
        int l = q >> 3, e = q & 7;
        int k = kb * 32 + ((l >> 4) << 3) + e;
        int col = (c2 << 4) + (l & 15);
        w2f[idx] = (__bf16)W2[k * NH2 + col];
    }
    if (idx < KDIM) {
        const float* b = basis + idx * 5;
        float n2 = b[0]*b[0] + b[1]*b[1] + b[2]*b[2] + b[3]*b[3] + b[4]*b[4];
        float* o = bp + idx * 8;
        o[0] = b[0]; o[1] = b[1]; o[2] = b[2]; o[3] = b[3]; o[4] = b[4];
        o[5] = 1.0f;
        o[6] = head_w[idx] * expf(-n2);   // gamma = 1
        o[7] = 0.0f;
    }
}

// ---------------------------------------------------------------------------
// fused main = R4 champion structure + WAR-race-fix barrier + NT x-stream.
//   block = 4 waves, tile 128 rows x 128 cols, BK=32.
//   A (x, f32, NT) + B (w1f frags) staged via global_load_lds into a 3-deep
//   LDS ring; stage(t+3) issued at iter t AFTER a barrier (all waves done
//   reading the buffer), waited with counted vmcnt(12) -> 2 stages always
//   in flight. A sources XOR-pre-swizzled (chunk ^= row&7) -> linear LDS,
//   conflict-free swizzled ds_read_b128.
// LDS map (73728 B): A ring 3x16K @0; B ring 3x8K @49152;
//   post-loop overlays: h1 4x8K @0; z5s @49152; psum @53248.
// ---------------------------------------------------------------------------
__launch_bounds__(256)
__global__ void fused_main(const float* __restrict__ x,
                           const __bf16* __restrict__ w1f,
                           const float* __restrict__ b1,
                           const __bf16* __restrict__ w2f,
                           const float* __restrict__ b2,
                           const float* __restrict__ W3,
                           const float* __restrict__ b3,
                           const float* __restrict__ conv_k,
                           const float* __restrict__ conv_b,
                           const float* __restrict__ bp,
                           const float* __restrict__ head_b,
                           float* __restrict__ out) {
    __shared__ __align__(16) char smem[73728];

    const int tid = threadIdx.x;
    const int w = tid >> 6;
    const int l = tid & 63;
    const int r = l & 15;        // fragment col/row index
    const int j = l >> 4;        // fragment k-group
    const int row0 = blockIdx.x * 128;

    // ---- staging source pointers (per lane) ------------------------------
    // A: instr q covers rows w*32+q*8 .. +8; lane: row += l>>3, slot l&7
    //    holds global 16B chunk (l&7)^(l>>3)  (XOR source pre-swizzle).
    const float* aSrc[4];
#pragma unroll
    for (int q = 0; q < 4; ++q)
        aSrc[q] = x + (size_t)(row0 + w * 32 + q * 8 + (l >> 3)) * IN_DIM
                    + (((l & 7) ^ (l >> 3)) << 2);
    // B: linear copy of the 8KB fragment tile; instr i = w*2+q covers 1KB.
    const __bf16* bSrc[2];
#pragma unroll
    for (int q = 0; q < 2; ++q)
        bSrc[q] = w1f + (w * 2 + q) * 512 + l * 8;

#define STAGE_ISSUE(AO, BO)                                                   \
    {                                                                         \
        _Pragma("unroll")                                                     \
        for (int q = 0; q < 4; ++q)                                           \
            gld16nt(aSrc[q], smem + (AO) + (w * 32 + q * 8) * 128);           \
        _Pragma("unroll")                                                     \
        for (int q = 0; q < 2; ++q)                                           \
            gld16(bSrc[q], smem + (BO) + (w * 2 + q) * 1024);                 \
    }
#define ADVANCE()                                                             \
    {                                                                         \
        _Pragma("unroll") for (int q = 0; q < 4; ++q) aSrc[q] += 32;          \
        _Pragma("unroll") for (int q = 0; q < 2; ++q) bSrc[q] += 4096;        \
    }

    f32x4 acc[2][8];
#pragma unroll
    for (int g = 0; g < 2; ++g)
#pragma unroll
        for (int c = 0; c < 8; ++c) acc[g][c] = (f32x4){0.f, 0.f, 0.f, 0.f};

#define KSTEP(AO, BO)                                                         \
    {                                                                         \
        bf16x8 Bv[8];                                                         \
        _Pragma("unroll")                                                     \
        for (int c = 0; c < 8; ++c)                                           \
            Bv[c] = *(const bf16x8*)(smem + (BO) + (c << 10) + l * 16);       \
        _Pragma("unroll")                                                     \
        for (int g = 0; g < 2; ++g) {                                         \
            const char* ab = smem + (AO) + (w * 32 + g * 16 + r) * 128;       \
            f32x4 f0 = *(const f32x4*)(ab + (((2 * j)     ^ (r & 7)) << 4));  \
            f32x4 f1 = *(const f32x4*)(ab + (((2 * j + 1) ^ (r & 7)) << 4));  \
            bf16x8 Af;                                                        \
            Af[0] = (__bf16)f0.x; Af[1] = (__bf16)f0.y;                       \
            Af[2] = (__bf16)f0.z; Af[3] = (__bf16)f0.w;                       \
            Af[4] = (__bf16)f1.x; Af[5] = (__bf16)f1.y;                       \
            Af[6] = (__bf16)f1.z; Af[7] = (__bf16)f1.w;                       \
            _Pragma("unroll")                                                 \
            for (int c = 0; c < 8; ++c)                                       \
                acc[g][c] = mfma16(Af, Bv[c], acc[g][c]);                     \
        }                                                                     \
    }

    // ---- prologue: fill the 3-deep ring ----------------------------------
    STAGE_ISSUE(0, 49152)      ADVANCE()
    STAGE_ISSUE(16384, 57344)  ADVANCE()
    STAGE_ISSUE(32768, 65536)  ADVANCE()
    asm volatile("s_waitcnt vmcnt(12)" ::: "memory");   // stage(0) done
    __builtin_amdgcn_s_barrier();
    __builtin_amdgcn_sched_barrier(0);

    unsigned aoff = 0, boff = 49152;
    // ---- main K-loop: t = 0..60 stage t+3; 61/62/63 drain ----------------
#pragma unroll 1
    for (int t = 0; t < 61; ++t) {
        KSTEP(aoff, boff)
        __builtin_amdgcn_s_barrier();    // all waves done reading buffer t
        __builtin_amdgcn_sched_barrier(0);
        STAGE_ISSUE(aoff, boff)          // stage(t+3) into freed buffer
        ADVANCE()
        asm volatile("s_waitcnt vmcnt(12)" ::: "memory");  // stage(t+1) done
        __builtin_amdgcn_s_barrier();
        __builtin_amdgcn_sched_barrier(0);
        aoff = (aoff == 32768u) ? 0u : aoff + 16384u;
        boff = (boff == 65536u) ? 49152u : boff + 8192u;
    }
    KSTEP(aoff, boff)                                       // t = 61
    asm volatile("s_waitcnt vmcnt(6)" ::: "memory");
    __builtin_amdgcn_s_barrier();
    __builtin_amdgcn_sched_barrier(0);
    aoff = (aoff == 32768u) ? 0u : aoff + 16384u;
    boff = (boff == 65536u) ? 49152u : boff + 8192u;
    KSTEP(aoff, boff)                                       // t = 62
    asm volatile("s_waitcnt vmcnt(0)" ::: "memory");
    __builtin_amdgcn_s_barrier();
    __builtin_amdgcn_sched_barrier(0);
    aoff = (aoff == 32768u) ? 0u : aoff + 16384u;
    boff = (boff == 65536u) ? 49152u : boff + 8192u;
    KSTEP(aoff, boff)                                       // t = 63

    __syncthreads();   // everyone done reading the ring; safe to overlay

    // ---- epilogue: + b1, relu, bf16 -> wave-private h1 tile --------------
    float b1v[8];
#pragma unroll
    for (int c = 0; c < 8; ++c) b1v[c] = b1[c * 16 + r];
    __bf16* hw1 = (__bf16*)(smem + w * 8192);
#pragma unroll
    for (int c = 0; c < 8; ++c)
#pragma unroll
        for (int g = 0; g < 2; ++g)
#pragma unroll
            for (int rr = 0; rr < 4; ++rr)
                hw1[(g * 16 + j * 4 + rr) * NH1 + c * 16 + r] =
                    (__bf16)fmaxf(acc[g][c][rr] + b1v[c], 0.f);

    // ---- stage 2: h2 = relu(h1 @ W2 + b2), wave-private ------------------
    f32x4 acc2[2][4];
#pragma unroll
    for (int g = 0; g < 2; ++g)
#pragma unroll
        for (int c2 = 0; c2 < 4; ++c2) acc2[g][c2] = (f32x4){0.f, 0.f, 0.f, 0.f};

#pragma unroll
    for (int kb = 0; kb < 4; ++kb) {
        bf16x8 A0 = *(const bf16x8*)&hw1[r * NH1 + kb * 32 + j * 8];
        bf16x8 A1 = *(const bf16x8*)&hw1[(16 + r) * NH1 + kb * 32 + j * 8];
#pragma unroll
        for (int c2 = 0; c2 < 4; ++c2) {
            bf16x8 B = *(const bf16x8*)(w2f + (((c2 << 2) + kb) << 9) + l * 8);
            acc2[0][c2] = mfma16(A0, B, acc2[0][c2]);
            acc2[1][c2] = mfma16(A1, B, acc2[1][c2]);
        }
    }

    // ---- stage 3: z = h2 @ W3 + b3 ; conv sigmoid ------------------------
    float b2v[4];
#pragma unroll
    for (int c2 = 0; c2 < 4; ++c2) b2v[c2] = b2[c2 * 16 + r];
    float w3l[4][4];
#pragma unroll
    for (int c2 = 0; c2 < 4; ++c2) {
        f32x4 t4 = *(const f32x4*)&W3[(c2 * 16 + r) * 4];
        w3l[c2][0] = t4.x; w3l[c2][1] = t4.y;
        w3l[c2][2] = t4.z; w3l[c2][3] = t4.w;
    }
    float h2v[2][4][4];
#pragma unroll
    for (int g = 0; g < 2; ++g)
#pragma unroll
        for (int c2 = 0; c2 < 4; ++c2)
#pragma unroll
            for (int rr = 0; rr < 4; ++rr)
                h2v[g][c2][rr] = fmaxf(acc2[g][c2][rr] + b2v[c2], 0.f);

    float pz[2][4][4];
#pragma unroll
    for (int g = 0; g < 2; ++g)
#pragma unroll
        for (int rr = 0; rr < 4; ++rr)
#pragma unroll
            for (int jj = 0; jj < 4; ++jj) {
                float s = 0.f;
#pragma unroll
                for (int c2 = 0; c2 < 4; ++c2)
                    s = fmaf(h2v[g][c2][rr], w3l[c2][jj], s);
                pz[g][rr][jj] = s;
            }
#pragma unroll
    for (int off = 1; off < 16; off <<= 1)
#pragma unroll
        for (int g = 0; g < 2; ++g)
#pragma unroll
            for (int rr = 0; rr < 4; ++rr)
#pragma unroll
                for (int jj = 0; jj < 4; ++jj)
                    pz[g][rr][jj] += __shfl_xor(pz[g][rr][jj], off, 64);

    const float ck0 = conv_k[0], ck1 = conv_k[1], ck2 = conv_k[2], ck3 = conv_k[3];
    const float cbv = conv_b[0];
    const float b30 = b3[0], b31 = b3[1], b32 = b3[2], b33 = b3[3];
    const float L2E = 1.44269504088896340736f;

    float (*z5s)[8] = (float(*)[8])(smem + 49152);
    float* psum = (float*)(smem + 53248);

    if (r == 0) {
#pragma unroll
        for (int g = 0; g < 2; ++g)
#pragma unroll
            for (int rr = 0; rr < 4; ++rr) {
                int rl = w * 32 + g * 16 + (j << 2) + rr;
                float z0 = pz[g][rr][0] + b30;
                float z1 = pz[g][rr][1] + b31;
                float z2 = pz[g][rr][2] + b32;
                float z3 = pz[g][rr][3] + b33;
                float s = fmaf(z0, ck0, fmaf(z1, ck1, fmaf(z2, ck2, fmaf(z3, ck3, cbv))));
                float sg = 1.f / (1.f + expf(-s));
                float n2 = z0*z0 + z1*z1 + z2*z2 + z3*z3 + sg*sg;
                z5s[rl][0] = 2.f * L2E * z0;
                z5s[rl][1] = 2.f * L2E * z1;
                z5s[rl][2] = 2.f * L2E * z2;
                z5s[rl][3] = 2.f * L2E * z3;
                z5s[rl][4] = 2.f * L2E * sg;
                z5s[rl][5] = -L2E * n2;
            }
    }
    __syncthreads();

    // ---- stage 4: RBF + head (128 rows, 2 half-splits of 512 basis) ------
    const int row = tid & 127;
    const int half = tid >> 7;
    f32x4 za = *(const f32x4*)&z5s[row][0];
    float z4s = z5s[row][4];
    float z5c = z5s[row][5];
    const float* bpp = bp + (size_t)half * 512 * 8;
    float accum = 0.f;
#pragma unroll 4
    for (int jb = 0; jb < 512; ++jb) {
        f32x4 q0 = *(const f32x4*)&bpp[jb * 8];
        f32x4 q1 = *(const f32x4*)&bpp[jb * 8 + 4];
        float arg = fmaf(za.x, q0.x,
                    fmaf(za.y, q0.y,
                    fmaf(za.z, q0.z,
                    fmaf(za.w, q0.w,
                    fmaf(z4s, q1.x, z5c)))));
        accum = fmaf(q1.z, exp2f(arg), accum);
    }
    if (half) psum[row] = accum;
    __syncthreads();
    if (!half) out[blockIdx.x * 128 + row] = accum + psum[row] + head_b[0];
}

// ---------------------------------------------------------------------------
extern "C" void kernel_launch(void* const* d_in, const int* in_sizes, int n_in,
                              void* d_out, int out_size, void* d_ws, size_t ws_size,
                              hipStream_t stream) {
    const float* x     = (const float*)d_in[0];
    const float* W1    = (const float*)d_in[1];
    const float* b1    = (const float*)d_in[2];
    const float* W2    = (const float*)d_in[3];
    const float* b2    = (const float*)d_in[4];
    const float* W3    = (const float*)d_in[5];
    const float* b3    = (const float*)d_in[6];
    const float* ck    = (const float*)d_in[7];
    const float* cb    = (const float*)d_in[8];
    const float* basis = (const float*)d_in[9];
    const float* hwv   = (const float*)d_in[10];
    const float* hb    = (const float*)d_in[11];

    __bf16* w1f = (__bf16*)d_ws;                                 // 524288 B
    __bf16* w2f = (__bf16*)((char*)d_ws + 524288);               // 16384 B
    float*  bpp = (float*)((char*)d_ws + 524288 + 16384);        // 32768 B

    prep_kernel<<<1024, 256, 0, stream>>>(W1, W2, basis, hwv, w1f, w2f, bpp);
    fused_main<<<512, 256, 0, stream>>>(x, w1f, b1, w2f, b2, W3, b3, ck, cb,
                                        bpp, hb, (float*)d_out);
}